// Round 8
// baseline (151.531 us; speedup 1.0000x reference)
//
#include <hip/hip_runtime.h>

#define B 8
#define NH 512
#define D 128
#define HEADS 4
#define ALPHA 0.2f

typedef short short8 __attribute__((ext_vector_type(8)));
typedef float f32x4 __attribute__((ext_vector_type(4)));
typedef unsigned short u16t;

__device__ __forceinline__ unsigned short f2b(float f) {
    union { float f; unsigned u; } v; v.f = f;
    unsigned r = v.u + 0x7FFFu + ((v.u >> 16) & 1u);
    return (unsigned short)(r >> 16);
}
__device__ __forceinline__ float b2f(unsigned short s) {
    union { unsigned u; float f; } v; v.u = ((unsigned)s) << 16;
    return v.f;
}
__device__ __forceinline__ float lrelu(float x) { return fmaxf(x, ALPHA * x); }
// pack two f32 -> two bf16 (truncation) in one v_perm
__device__ __forceinline__ unsigned packbf(float a, float b) {
    union { float f; unsigned u; } ua, ub; ua.f = a; ub.f = b;
    return __builtin_amdgcn_perm(ub.u, ua.u, 0x07060302u);
}
// pack two f32 -> two bf16 with RNE rounding (matches f2b)
__device__ __forceinline__ unsigned packbf_rne(float a, float b) {
    return (unsigned)f2b(a) | ((unsigned)f2b(b) << 16);
}
__device__ __forceinline__ unsigned long long pack4_rne(f32x4 v) {
    return (unsigned long long)packbf_rne(v[0], v[1])
         | ((unsigned long long)packbf_rne(v[2], v[3]) << 32);
}

// ============ proj1: h1T[bh][c][n] = (x @ Wh)^T, + f1a/f2a =================
// grid 512 (128 row-tiles of 64 x 4 heads), 256 thr.
// Side-job: bid<128 emit WoT[c][k]=bf16(Wo[k][c]).
__global__ __launch_bounds__(256) void proj1_kernel(
    const float* __restrict__ hs, const float* __restrict__ os,
    const float* __restrict__ Wh, const float* __restrict__ Wo,
    const float* __restrict__ ah,
    u16t* __restrict__ h1T, u16t* __restrict__ WoT,
    float* __restrict__ f1, float* __restrict__ f2)
{
    int bid = blockIdx.x;
    int rt = bid >> 2, h = bid & 3;
    int rowG = rt * 64;
    int b = rowG >> 10;
    int t = threadIdx.x;
    int w = t >> 6, l = t & 63, l15 = l & 15, g = l >> 4;

    __shared__ __align__(16) u16t wlds[128][136];   // [c][k], pad 8

    // stage W[h]^T into LDS
    {
        const float* Whh = Wh + (size_t)h * 16384;
        #pragma unroll
        for (int i = 0; i < 32; ++i) {
            int p = i * 256 + t;
            int c = p & 127, k0 = (p >> 7) * 2;
            float w0 = Whh[(size_t)k0 * 128 + c];
            float w1 = Whh[(size_t)(k0 + 1) * 128 + c];
            *(unsigned*)&wlds[c][k0] = packbf_rne(w0, w1);
        }
    }
    // side job: emit WoT (128 blocks x 256 thr x 2 elems)
    if (bid < 128) {
        int idx = bid * 512 + t * 2;
        int c = idx >> 9, k = idx & 511;
        float w0 = Wo[(size_t)k * 128 + c];
        float w1 = Wo[(size_t)(k + 1) * 128 + c];
        *(unsigned*)&WoT[(size_t)c * 512 + k] = packbf_rne(w0, w1);
    }
    __syncthreads();

    int nA = rowG + w * 16 + l15;
    int nloc = nA & 1023;
    const float* xr = (nloc < NH) ? hs + ((size_t)(b * NH + nloc)) * 128
                                  : os + ((size_t)(b * NH + (nloc - NH))) * 128;

    f32x4 acc[8] = {};
    #pragma unroll
    for (int kc = 0; kc < 4; ++kc) {
        int k0 = kc * 32 + g * 8;
        float4 u0 = *(const float4*)&xr[k0];
        float4 u1 = *(const float4*)&xr[k0 + 4];
        union { unsigned u[4]; short8 s; } afu;
        afu.u[0] = packbf_rne(u0.x, u0.y);
        afu.u[1] = packbf_rne(u0.z, u0.w);
        afu.u[2] = packbf_rne(u1.x, u1.y);
        afu.u[3] = packbf_rne(u1.z, u1.w);
        short8 af = afu.s;
        #pragma unroll
        for (int ct = 0; ct < 8; ++ct) {
            short8 bfr = *(const short8*)&wlds[ct * 16 + l15][k0];
            acc[ct] = __builtin_amdgcn_mfma_f32_16x16x32_bf16(af, bfr, acc[ct], 0, 0, 0);
        }
    }

    int bh = b * HEADS + h;
    size_t hTbase = (size_t)bh * 131072;
    int nloc0 = (rowG & 1023) + w * 16 + g * 4;
    float pr1[4] = {0.f, 0.f, 0.f, 0.f}, pr2[4] = {0.f, 0.f, 0.f, 0.f};

    #pragma unroll
    for (int ct = 0; ct < 8; ++ct) {
        int c = ct * 16 + l15;
        *(unsigned long long*)&h1T[hTbase + (size_t)c * 1024 + nloc0] = pack4_rne(acc[ct]);
        float a1 = ah[h * 256 + c], a2 = ah[h * 256 + 128 + c];
        #pragma unroll
        for (int r = 0; r < 4; ++r) {
            pr1[r] = fmaf(acc[ct][r], a1, pr1[r]);
            pr2[r] = fmaf(acc[ct][r], a2, pr2[r]);
        }
    }
    #pragma unroll
    for (int r = 0; r < 4; ++r) {
        float v1 = pr1[r], v2 = pr2[r];
        #pragma unroll
        for (int m = 1; m <= 8; m <<= 1) {
            v1 += __shfl_xor(v1, m, 64);
            v2 += __shfl_xor(v2, m, 64);
        }
        if (l15 == 0) {
            f1[(size_t)bh * 1024 + nloc0 + r] = v1;
            f2[(size_t)bh * 1024 + nloc0 + r] = v2;
        }
    }
}

// ============ attn0: x2 = elu(softmax(e) @ H) per head, bf16 ===============
// 512 blocks (XCD-swizzled: 64 q=(z,side) x 8 itiles of 64 rows)
__global__ __launch_bounds__(256) void attn0_kernel(
    const u16t* __restrict__ HT,                    // [Z][128][1024] bf16
    const float* __restrict__ f1, const float* __restrict__ f2,  // [Z][1024]
    u16t* __restrict__ x2)                          // [8192][512] bf16
{
    __shared__ __align__(16) u16t hbuf[2][128][40];
    __shared__ __align__(16) float f2s[512];
    __shared__ float red4[4];

    int t = threadIdx.x, w4 = t >> 6, l = t & 63, l15 = l & 15, g = l >> 4;
    int wid = blockIdx.x;
    int xcd = wid & 7, jj = (wid >> 3) & 7;
    int itile = wid >> 6;
    int q = xcd * 8 + jj;
    int z = q >> 1, side = q & 1;
    int b = z >> 2, h = z & 3;
    bool self = (side == 0);
    int nbBase = self ? 512 : 0;
    size_t HTbase = (size_t)z * 131072;
    size_t fbase = (size_t)z * 1024;

    f2s[t] = f2[fbase + nbBase + t];
    f2s[t + 256] = f2[fbase + nbBase + t + 256];
    __syncthreads();
    float mv = fmaxf(f2s[t], f2s[t + 256]);
    #pragma unroll
    for (int m = 1; m <= 32; m <<= 1) mv = fmaxf(mv, __shfl_xor(mv, m, 64));
    if (l == 0) red4[w4] = mv;
    __syncthreads();
    float M = fmaxf(fmaxf(red4[0], red4[1]), fmaxf(red4[2], red4[3]));

    int i0 = itile * 64 + w4 * 16;
    int i = i0 + l15;
    int n = side * 512 + i;
    float fv = f1[fbase + n];
    float mr = lrelu(fv + M);
    float z0 = 0.f;
    if (self) {
        float sc = lrelu(fv + f2[fbase + i]);
        mr = fmaxf(mr, sc);
        z0 = __expf(sc - mr);
    }
    float zacc = (g == 0) ? z0 : 0.f;

    {
        int c = t >> 1, ks = (t & 1) * 16;
        const u16t* src = &HT[HTbase + (size_t)c * 1024 + nbBase + ks];
        *(short8*)&hbuf[0][c][ks] = *(const short8*)src;
        *(short8*)&hbuf[0][c][ks + 8] = *(const short8*)(src + 8);
    }
    __syncthreads();

    f32x4 acc[8] = {};
    int cS = t >> 1, ksS = (t & 1) * 16;

    for (int jt = 0; jt < 16; ++jt) {
        int cur = jt & 1;
        short8 s0, s1;
        if (jt < 15) {
            const u16t* src = &HT[HTbase + (size_t)cS * 1024 + nbBase + (jt + 1) * 32 + ksS];
            s0 = *(const short8*)src;
            s1 = *(const short8*)(src + 8);
        }
        int j0 = jt * 32 + g * 8;
        float p[8];
        #pragma unroll
        for (int qq = 0; qq < 8; ++qq) {
            float tq = fv + f2s[j0 + qq];
            float ev = fmaxf(tq, ALPHA * tq);
            p[qq] = __expf(ev - mr);
            zacc += p[qq];
        }
        union { unsigned u[4]; short8 s; } pfu;
        pfu.u[0] = packbf(p[0], p[1]);
        pfu.u[1] = packbf(p[2], p[3]);
        pfu.u[2] = packbf(p[4], p[5]);
        pfu.u[3] = packbf(p[6], p[7]);
        short8 pf = pfu.s;
        #pragma unroll
        for (int ct = 0; ct < 8; ++ct) {
            short8 hf = *(const short8*)&hbuf[cur][ct * 16 + l15][g * 8];
            acc[ct] = __builtin_amdgcn_mfma_f32_16x16x32_bf16(hf, pf, acc[ct], 0, 0, 0);
        }
        if (jt < 15) {
            *(short8*)&hbuf[cur ^ 1][cS][ksS] = s0;
            *(short8*)&hbuf[cur ^ 1][cS][ksS + 8] = s1;
        }
        __syncthreads();
    }

    // self-loop via diagonal-B MFMA
    if (self) {
        unsigned short z0b = f2b(z0);
        short8 pfs;
        #pragma unroll
        for (int qq = 0; qq < 8; ++qq)
            pfs[qq] = (short)((g * 8 + qq == l15) ? z0b : 0);
        int sc0 = side * 512 + i0;
        #pragma unroll
        for (int ct = 0; ct < 8; ++ct) {
            short8 hfs = *(const short8*)&HT[HTbase + (size_t)(ct * 16 + l15) * 1024 + sc0 + g * 8];
            acc[ct] = __builtin_amdgcn_mfma_f32_16x16x32_bf16(hfs, pfs, acc[ct], 0, 0, 0);
        }
    }

    zacc += __shfl_xor(zacc, 16, 64);
    zacc += __shfl_xor(zacc, 32, 64);
    float zinv = 1.f / zacc;

    size_t orow = ((size_t)(b * 1024 + n)) * 512 + h * 128;
    #pragma unroll
    for (int ct = 0; ct < 8; ++ct) {
        int c0 = ct * 16 + g * 4;
        float o[4];
        #pragma unroll
        for (int r = 0; r < 4; ++r) {
            float v = acc[ct][r] * zinv;
            o[r] = v > 0.f ? v : __expf(v) - 1.f;
        }
        unsigned long long pv =
              (unsigned long long)packbf_rne(o[0], o[1])
            | ((unsigned long long)packbf_rne(o[2], o[3]) << 32);
        *(unsigned long long*)&x2[orow + c0] = pv;
    }
}

// ============ final: fused proj2 + attn1 (layer-2) =========================
// 64 blocks (8 b x 8 itiles of 64 human rows), 256 thr.
// Phase A: own-rows h2 GEMM (K=512) -> LDS h2ownT + f1own/f2own.
// Phase B: 8 chunks of 64 objects: chunk h2 GEMM -> LDS h2oT + f2s;
//          online-softmax P; 2 PV MFMAs per ct. Self folded via z0 at end.
// Epilogue: elu + log_softmax -> dout.
__global__ __launch_bounds__(256) void final_kernel(
    const u16t* __restrict__ x2,                    // [8192][512] bf16
    const u16t* __restrict__ WoT,                   // [128][512] bf16
    const float* __restrict__ ao,                   // [256] f32
    float* __restrict__ dout)                       // [B*512][128] f32
{
    __shared__ __align__(16) u16t h2oT[128][72];    // [c][n-pad] chunk objects
    __shared__ __align__(16) u16t h2ownT[128][72];  // [c][n-pad] own humans
    __shared__ float f2s[64];
    __shared__ float f1own[64], f2own[64];

    int t = threadIdx.x, w4 = t >> 6, l = t & 63, l15 = l & 15, g = l >> 4;
    int b = blockIdx.x & 7, itile = blockIdx.x >> 3;

    // hoisted a_out fragments (c = ct*16 + l15)
    float ao1f[8], ao2f[8];
    #pragma unroll
    for (int ct = 0; ct < 8; ++ct) {
        ao1f[ct] = ao[ct * 16 + l15];
        ao2f[ct] = ao[128 + ct * 16 + l15];
    }

    int n0 = w4 * 16 + g * 4;                       // lane's 4-row base (C-frag)

    // ---- Phase A: own human rows ----
    {
        int rowA = b * 1024 + itile * 64 + w4 * 16 + l15;
        f32x4 accG[8] = {};
        #pragma unroll
        for (int kc = 0; kc < 16; ++kc) {
            int k0 = kc * 32 + g * 8;
            short8 af = *(const short8*)&x2[(size_t)rowA * 512 + k0];
            #pragma unroll
            for (int ct = 0; ct < 8; ++ct) {
                short8 bfr = *(const short8*)&WoT[(size_t)(ct * 16 + l15) * 512 + k0];
                accG[ct] = __builtin_amdgcn_mfma_f32_16x16x32_bf16(af, bfr, accG[ct], 0, 0, 0);
            }
        }
        float pr1[4] = {0.f, 0.f, 0.f, 0.f}, pr2[4] = {0.f, 0.f, 0.f, 0.f};
        #pragma unroll
        for (int ct = 0; ct < 8; ++ct) {
            *(unsigned long long*)&h2ownT[ct * 16 + l15][n0] = pack4_rne(accG[ct]);
            #pragma unroll
            for (int r = 0; r < 4; ++r) {
                pr1[r] = fmaf(accG[ct][r], ao1f[ct], pr1[r]);
                pr2[r] = fmaf(accG[ct][r], ao2f[ct], pr2[r]);
            }
        }
        #pragma unroll
        for (int r = 0; r < 4; ++r) {
            float v1 = pr1[r], v2 = pr2[r];
            #pragma unroll
            for (int m = 1; m <= 8; m <<= 1) {
                v1 += __shfl_xor(v1, m, 64);
                v2 += __shfl_xor(v2, m, 64);
            }
            if (l15 == 0) { f1own[n0 + r] = v1; f2own[n0 + r] = v2; }
        }
    }
    __syncthreads();

    float fv = f1own[w4 * 16 + l15];
    float sc = lrelu(fv + f2own[w4 * 16 + l15]);
    float mr = sc;                                   // self score = initial max
    float zacc = 0.f;
    f32x4 acc[8] = {};

    // ---- Phase B: 8 chunks of 64 objects ----
    for (int ch = 0; ch < 8; ++ch) {
        int rowO = b * 1024 + 512 + ch * 64 + w4 * 16 + l15;
        f32x4 accG[8] = {};
        #pragma unroll
        for (int kc = 0; kc < 16; ++kc) {
            int k0 = kc * 32 + g * 8;
            short8 af = *(const short8*)&x2[(size_t)rowO * 512 + k0];
            #pragma unroll
            for (int ct = 0; ct < 8; ++ct) {
                short8 bfr = *(const short8*)&WoT[(size_t)(ct * 16 + l15) * 512 + k0];
                accG[ct] = __builtin_amdgcn_mfma_f32_16x16x32_bf16(af, bfr, accG[ct], 0, 0, 0);
            }
        }
        float v2r[4];
        {
            float pr2[4] = {0.f, 0.f, 0.f, 0.f};
            #pragma unroll
            for (int ct = 0; ct < 8; ++ct)
                #pragma unroll
                for (int r = 0; r < 4; ++r)
                    pr2[r] = fmaf(accG[ct][r], ao2f[ct], pr2[r]);
            #pragma unroll
            for (int r = 0; r < 4; ++r) {
                float v2 = pr2[r];
                #pragma unroll
                for (int m = 1; m <= 8; m <<= 1) v2 += __shfl_xor(v2, m, 64);
                v2r[r] = v2;
            }
        }
        __syncthreads();                             // prev PV done with h2oT
        #pragma unroll
        for (int ct = 0; ct < 8; ++ct)
            *(unsigned long long*)&h2oT[ct * 16 + l15][n0] = pack4_rne(accG[ct]);
        if (l15 == 0) {
            #pragma unroll
            for (int r = 0; r < 4; ++r) f2s[n0 + r] = v2r[r];
        }
        __syncthreads();

        // online softmax for this chunk (64 j's; lane covers 16)
        float p[16];
        float cm = -3.0e38f;
        #pragma unroll
        for (int qq = 0; qq < 8; ++qq) {
            float t0 = fv + f2s[g * 8 + qq];
            float t1 = fv + f2s[32 + g * 8 + qq];
            float e0 = fmaxf(t0, ALPHA * t0);
            float e1 = fmaxf(t1, ALPHA * t1);
            p[qq] = e0; p[8 + qq] = e1;
            cm = fmaxf(cm, fmaxf(e0, e1));
        }
        cm = fmaxf(cm, __shfl_xor(cm, 16, 64));
        cm = fmaxf(cm, __shfl_xor(cm, 32, 64));
        float mnew = fmaxf(mr, cm);
        float scl = __expf(mr - mnew);
        mr = mnew;
        zacc *= scl;
        #pragma unroll
        for (int ct = 0; ct < 8; ++ct) acc[ct] *= scl;
        float zs = 0.f;
        #pragma unroll
        for (int qq = 0; qq < 16; ++qq) {
            p[qq] = __expf(p[qq] - mr);
            zs += p[qq];
        }
        zacc += zs;
        union { unsigned u[4]; short8 s; } pa, pb;
        pa.u[0] = packbf(p[0], p[1]);  pa.u[1] = packbf(p[2], p[3]);
        pa.u[2] = packbf(p[4], p[5]);  pa.u[3] = packbf(p[6], p[7]);
        pb.u[0] = packbf(p[8], p[9]);  pb.u[1] = packbf(p[10], p[11]);
        pb.u[2] = packbf(p[12], p[13]); pb.u[3] = packbf(p[14], p[15]);
        #pragma unroll
        for (int ct = 0; ct < 8; ++ct) {
            short8 hf0 = *(const short8*)&h2oT[ct * 16 + l15][g * 8];
            acc[ct] = __builtin_amdgcn_mfma_f32_16x16x32_bf16(hf0, pa.s, acc[ct], 0, 0, 0);
            short8 hf1 = *(const short8*)&h2oT[ct * 16 + l15][32 + g * 8];
            acc[ct] = __builtin_amdgcn_mfma_f32_16x16x32_bf16(hf1, pb.s, acc[ct], 0, 0, 0);
        }
    }

    zacc += __shfl_xor(zacc, 16, 64);
    zacc += __shfl_xor(zacc, 32, 64);
    float z0 = __expf(sc - mr);
    float zinv = 1.f / (zacc + z0);

    // epilogue: self-add + elu + log_softmax (lane l15 = human i; c = ct*16+g*4+r)
    int i = itile * 64 + w4 * 16 + l15;
    float o[8][4];
    float mx = -3.0e38f;
    #pragma unroll
    for (int ct = 0; ct < 8; ++ct) {
        #pragma unroll
        for (int r = 0; r < 4; ++r) {
            int c = ct * 16 + g * 4 + r;
            float hv = b2f(h2ownT[c][w4 * 16 + l15]);
            float v = (acc[ct][r] + z0 * hv) * zinv;
            v = v > 0.f ? v : __expf(v) - 1.f;
            o[ct][r] = v;
            mx = fmaxf(mx, v);
        }
    }
    mx = fmaxf(mx, __shfl_xor(mx, 16, 64));
    mx = fmaxf(mx, __shfl_xor(mx, 32, 64));
    float s = 0.f;
    #pragma unroll
    for (int ct = 0; ct < 8; ++ct)
        #pragma unroll
        for (int r = 0; r < 4; ++r) s += __expf(o[ct][r] - mx);
    s += __shfl_xor(s, 16, 64);
    s += __shfl_xor(s, 32, 64);
    float lse = mx + __logf(s);
    #pragma unroll
    for (int ct = 0; ct < 8; ++ct) {
        float4 st = {o[ct][0] - lse, o[ct][1] - lse, o[ct][2] - lse, o[ct][3] - lse};
        *(float4*)&dout[((size_t)(b * 512 + i)) * 128 + ct * 16 + g * 4] = st;
    }
}

extern "C" void kernel_launch(void* const* d_in, const int* in_sizes, int n_in,
                              void* d_out, int out_size, void* d_ws, size_t ws_size,
                              hipStream_t stream)
{
    const float* hs = (const float*)d_in[0];
    const float* os = (const float*)d_in[1];
    const float* Wh = (const float*)d_in[4];
    const float* ah = (const float*)d_in[5];
    const float* Wo = (const float*)d_in[6];
    const float* ao = (const float*)d_in[7];
    float* out = (float*)d_out;

    u16t* h1T = (u16t*)d_ws;             // 4,194,304 u16
    u16t* x2  = h1T + 4194304;           // 4,194,304 u16
    u16t* WoT = x2 + 4194304;            // 65,536 u16
    float* f1a = (float*)(WoT + 65536);  // 32,768 f32
    float* f2a = f1a + 32768;            // 32,768 f32

    proj1_kernel<<<512, 256, 0, stream>>>(hs, os, Wh, Wo, ah, h1T, WoT, f1a, f2a);
    attn0_kernel<<<512, 256, 0, stream>>>(h1T, f1a, f2a, x2);
    final_kernel<<<64, 256, 0, stream>>>(x2, WoT, ao, out);
}

// Round 9
// 61.987 us; speedup vs baseline: 2.4446x; 2.4446x over previous
//
#include <hip/hip_runtime.h>

#define B 8
#define NH 512
#define D 128
#define HEADS 4
#define ALPHA 0.2f

typedef short short8 __attribute__((ext_vector_type(8)));
typedef float f32x4 __attribute__((ext_vector_type(4)));
typedef unsigned short u16t;

__device__ __forceinline__ unsigned short f2b(float f) {
    union { float f; unsigned u; } v; v.f = f;
    unsigned r = v.u + 0x7FFFu + ((v.u >> 16) & 1u);
    return (unsigned short)(r >> 16);
}
__device__ __forceinline__ float lrelu(float x) { return fmaxf(x, ALPHA * x); }
// pack two f32 -> two bf16 (truncation) in one v_perm
__device__ __forceinline__ unsigned packbf(float a, float b) {
    union { float f; unsigned u; } ua, ub; ua.f = a; ub.f = b;
    return __builtin_amdgcn_perm(ub.u, ua.u, 0x07060302u);
}
// pack two f32 -> two bf16 with RNE rounding (matches f2b)
__device__ __forceinline__ unsigned packbf_rne(float a, float b) {
    return (unsigned)f2b(a) | ((unsigned)f2b(b) << 16);
}
__device__ __forceinline__ unsigned long long pack4_rne(f32x4 v) {
    return (unsigned long long)packbf_rne(v[0], v[1])
         | ((unsigned long long)packbf_rne(v[2], v[3]) << 32);
}

// ============ proj1: h1T[bh][c][n] = (x @ Wh)^T, + f1a/f2a =================
// grid 256 (64 row-tiles of 128 x 4 heads), 512 thr (8 waves, 16 rows each).
// W[h] staged f32->bf16 transposed into LDS once per block (128-row tile
// halves the W re-staging traffic vs 64-row tiles).
// Side-job: bid<64 emit WoT[c][k]=bf16(Wo[k][c]).
__global__ __launch_bounds__(512) void proj1_kernel(
    const float* __restrict__ hs, const float* __restrict__ os,
    const float* __restrict__ Wh, const float* __restrict__ Wo,
    const float* __restrict__ ah,
    u16t* __restrict__ h1T, u16t* __restrict__ WoT,
    float* __restrict__ f1, float* __restrict__ f2)
{
    int bid = blockIdx.x;
    int rt = bid >> 2, h = bid & 3;
    int rowG = rt * 128;
    int b = rowG >> 10;
    int t = threadIdx.x;
    int w = t >> 6, l = t & 63, l15 = l & 15, g = l >> 4;

    __shared__ __align__(16) u16t wlds[128][136];   // [c][k], pad 8

    // stage W[h]^T into LDS: 8192 pairs / 512 thr = 16 iters
    {
        const float* Whh = Wh + (size_t)h * 16384;
        #pragma unroll
        for (int i = 0; i < 16; ++i) {
            int p = i * 512 + t;
            int c = p & 127, k0 = (p >> 7) * 2;
            float w0 = Whh[(size_t)k0 * 128 + c];
            float w1 = Whh[(size_t)(k0 + 1) * 128 + c];
            *(unsigned*)&wlds[c][k0] = packbf_rne(w0, w1);
        }
    }
    // side job: emit WoT (64 blocks x 512 thr x 2 elems = 65536)
    if (bid < 64) {
        int idx = bid * 1024 + t * 2;
        int c = idx >> 9, k = idx & 511;
        float w0 = Wo[(size_t)k * 128 + c];
        float w1 = Wo[(size_t)(k + 1) * 128 + c];
        *(unsigned*)&WoT[(size_t)c * 512 + k] = packbf_rne(w0, w1);
    }
    __syncthreads();

    int nA = rowG + w * 16 + l15;
    int nloc = nA & 1023;
    const float* xr = (nloc < NH) ? hs + ((size_t)(b * NH + nloc)) * 128
                                  : os + ((size_t)(b * NH + (nloc - NH))) * 128;

    f32x4 acc[8] = {};
    #pragma unroll
    for (int kc = 0; kc < 4; ++kc) {
        int k0 = kc * 32 + g * 8;
        float4 u0 = *(const float4*)&xr[k0];
        float4 u1 = *(const float4*)&xr[k0 + 4];
        union { unsigned u[4]; short8 s; } afu;
        afu.u[0] = packbf_rne(u0.x, u0.y);
        afu.u[1] = packbf_rne(u0.z, u0.w);
        afu.u[2] = packbf_rne(u1.x, u1.y);
        afu.u[3] = packbf_rne(u1.z, u1.w);
        short8 af = afu.s;
        #pragma unroll
        for (int ct = 0; ct < 8; ++ct) {
            short8 bfr = *(const short8*)&wlds[ct * 16 + l15][k0];
            acc[ct] = __builtin_amdgcn_mfma_f32_16x16x32_bf16(af, bfr, acc[ct], 0, 0, 0);
        }
    }

    int bh = b * HEADS + h;
    size_t hTbase = (size_t)bh * 131072;
    int nloc0 = (rowG & 1023) + w * 16 + g * 4;
    float pr1[4] = {0.f, 0.f, 0.f, 0.f}, pr2[4] = {0.f, 0.f, 0.f, 0.f};

    #pragma unroll
    for (int ct = 0; ct < 8; ++ct) {
        int c = ct * 16 + l15;
        *(unsigned long long*)&h1T[hTbase + (size_t)c * 1024 + nloc0] = pack4_rne(acc[ct]);
        float a1 = ah[h * 256 + c], a2 = ah[h * 256 + 128 + c];
        #pragma unroll
        for (int r = 0; r < 4; ++r) {
            pr1[r] = fmaf(acc[ct][r], a1, pr1[r]);
            pr2[r] = fmaf(acc[ct][r], a2, pr2[r]);
        }
    }
    #pragma unroll
    for (int r = 0; r < 4; ++r) {
        float v1 = pr1[r], v2 = pr2[r];
        #pragma unroll
        for (int m = 1; m <= 8; m <<= 1) {
            v1 += __shfl_xor(v1, m, 64);
            v2 += __shfl_xor(v2, m, 64);
        }
        if (l15 == 0) {
            f1[(size_t)bh * 1024 + nloc0 + r] = v1;
            f2[(size_t)bh * 1024 + nloc0 + r] = v2;
        }
    }
}

// ============ proj2: h2T[b][c][n] = (x2 @ Wo)^T, + f1b/f2b =================
// grid 128 (8192 rows / 64), 256 thr. x2 bf16 row-major [8192][512].
__global__ __launch_bounds__(256) void proj2_kernel(
    const u16t* __restrict__ x2, const u16t* __restrict__ WoT,
    const float* __restrict__ ao,
    u16t* __restrict__ h2T, float* __restrict__ f1, float* __restrict__ f2)
{
    int rowG = blockIdx.x * 64;
    int b = rowG >> 10;
    int t = threadIdx.x;
    int w = t >> 6, l = t & 63, l15 = l & 15, g = l >> 4;

    int rowA = rowG + w * 16 + l15;

    f32x4 acc[8] = {};
    #pragma unroll
    for (int kc = 0; kc < 16; ++kc) {
        int k0 = kc * 32 + g * 8;
        short8 af = *(const short8*)&x2[(size_t)rowA * 512 + k0];
        #pragma unroll
        for (int ct = 0; ct < 8; ++ct) {
            short8 bfr = *(const short8*)&WoT[(ct * 16 + l15) * 512 + k0];
            acc[ct] = __builtin_amdgcn_mfma_f32_16x16x32_bf16(af, bfr, acc[ct], 0, 0, 0);
        }
    }

    size_t hTbase = (size_t)b * 131072;
    int nloc0 = (rowG & 1023) + w * 16 + g * 4;
    int rowOut0 = rowG + w * 16 + g * 4;
    float pr1[4] = {0.f, 0.f, 0.f, 0.f}, pr2[4] = {0.f, 0.f, 0.f, 0.f};

    #pragma unroll
    for (int ct = 0; ct < 8; ++ct) {
        int c = ct * 16 + l15;
        *(unsigned long long*)&h2T[hTbase + (size_t)c * 1024 + nloc0] = pack4_rne(acc[ct]);
        float a1 = ao[c], a2 = ao[128 + c];
        #pragma unroll
        for (int r = 0; r < 4; ++r) {
            pr1[r] = fmaf(acc[ct][r], a1, pr1[r]);
            pr2[r] = fmaf(acc[ct][r], a2, pr2[r]);
        }
    }
    #pragma unroll
    for (int r = 0; r < 4; ++r) {
        float v1 = pr1[r], v2 = pr2[r];
        #pragma unroll
        for (int m = 1; m <= 8; m <<= 1) {
            v1 += __shfl_xor(v1, m, 64);
            v2 += __shfl_xor(v2, m, 64);
        }
        if (l15 == 0) { f1[rowOut0 + r] = v1; f2[rowOut0 + r] = v2; }
    }
}

// ============ attn: O^T = H^T · P^T (MFMA), self via diagonal MFMA =========
// mode 0: 512 blocks (XCD-swizzled: 64 q=(z,side) x 8 itiles of 64 rows)
// mode 1: 64 blocks (8 b x 8 itiles), + fused elu+log_softmax
__global__ __launch_bounds__(256) void attn_kernel(
    const u16t* __restrict__ HT,                    // [Z][128][1024] bf16
    const float* __restrict__ f1, const float* __restrict__ f2,  // [Z][1024]
    u16t* __restrict__ x2, float* __restrict__ dout, int mode)
{
    __shared__ __align__(16) u16t hbuf[2][128][40];
    __shared__ __align__(16) float f2s[512];
    __shared__ float red4[4];

    int t = threadIdx.x, w4 = t >> 6, l = t & 63, l15 = l & 15, g = l >> 4;
    int wid = blockIdx.x;
    int itile, side, z, b, h;
    if (mode == 0) {
        int xcd = wid & 7, jj = (wid >> 3) & 7;
        itile = wid >> 6;
        int q = xcd * 8 + jj;
        z = q >> 1; side = q & 1; b = z >> 2; h = z & 3;
    } else {
        b = wid & 7; itile = wid >> 3; side = 0; z = b; h = 0;
    }
    bool self = (side == 0);
    int nbBase = self ? 512 : 0;
    size_t HTbase = (size_t)z * 131072;
    size_t fbase = (size_t)z * 1024;

    f2s[t] = f2[fbase + nbBase + t];
    f2s[t + 256] = f2[fbase + nbBase + t + 256];
    __syncthreads();
    float mv = fmaxf(f2s[t], f2s[t + 256]);
    #pragma unroll
    for (int m = 1; m <= 32; m <<= 1) mv = fmaxf(mv, __shfl_xor(mv, m, 64));
    if (l == 0) red4[w4] = mv;
    __syncthreads();
    float M = fmaxf(fmaxf(red4[0], red4[1]), fmaxf(red4[2], red4[3]));

    int i0 = itile * 64 + w4 * 16;
    int i = i0 + l15;
    int n = side * 512 + i;
    float fv = f1[fbase + n];
    float mr = lrelu(fv + M);
    float z0 = 0.f;
    if (self) {
        float sc = lrelu(fv + f2[fbase + i]);
        mr = fmaxf(mr, sc);
        z0 = __expf(sc - mr);
    }
    float zacc = (g == 0) ? z0 : 0.f;

    {
        int c = t >> 1, ks = (t & 1) * 16;
        const u16t* src = &HT[HTbase + (size_t)c * 1024 + nbBase + ks];
        *(short8*)&hbuf[0][c][ks] = *(const short8*)src;
        *(short8*)&hbuf[0][c][ks + 8] = *(const short8*)(src + 8);
    }
    __syncthreads();

    f32x4 acc[8] = {};
    int cS = t >> 1, ksS = (t & 1) * 16;

    for (int jt = 0; jt < 16; ++jt) {
        int cur = jt & 1;
        short8 s0, s1;
        if (jt < 15) {
            const u16t* src = &HT[HTbase + (size_t)cS * 1024 + nbBase + (jt + 1) * 32 + ksS];
            s0 = *(const short8*)src;
            s1 = *(const short8*)(src + 8);
        }
        int j0 = jt * 32 + g * 8;
        float p[8];
        #pragma unroll
        for (int qq = 0; qq < 8; ++qq) {
            float tq = fv + f2s[j0 + qq];
            float ev = fmaxf(tq, ALPHA * tq);
            p[qq] = __expf(ev - mr);
            zacc += p[qq];
        }
        union { unsigned u[4]; short8 s; } pfu;
        pfu.u[0] = packbf(p[0], p[1]);
        pfu.u[1] = packbf(p[2], p[3]);
        pfu.u[2] = packbf(p[4], p[5]);
        pfu.u[3] = packbf(p[6], p[7]);
        short8 pf = pfu.s;
        #pragma unroll
        for (int ct = 0; ct < 8; ++ct) {
            short8 hf = *(const short8*)&hbuf[cur][ct * 16 + l15][g * 8];
            acc[ct] = __builtin_amdgcn_mfma_f32_16x16x32_bf16(hf, pf, acc[ct], 0, 0, 0);
        }
        if (jt < 15) {
            *(short8*)&hbuf[cur ^ 1][cS][ksS] = s0;
            *(short8*)&hbuf[cur ^ 1][cS][ksS + 8] = s1;
        }
        __syncthreads();
    }

    // self-loop via diagonal-B MFMA
    if (self) {
        unsigned short z0b = f2b(z0);
        short8 pfs;
        #pragma unroll
        for (int qq = 0; qq < 8; ++qq)
            pfs[qq] = (short)((g * 8 + qq == l15) ? z0b : 0);
        int sc0 = side * 512 + i0;
        #pragma unroll
        for (int ct = 0; ct < 8; ++ct) {
            short8 hfs = *(const short8*)&HT[HTbase + (size_t)(ct * 16 + l15) * 1024 + sc0 + g * 8];
            acc[ct] = __builtin_amdgcn_mfma_f32_16x16x32_bf16(hfs, pfs, acc[ct], 0, 0, 0);
        }
    }

    zacc += __shfl_xor(zacc, 16, 64);
    zacc += __shfl_xor(zacc, 32, 64);
    float zinv = 1.f / zacc;

    if (mode == 0) {
        size_t orow = ((size_t)(b * 1024 + n)) * 512 + h * 128;
        #pragma unroll
        for (int ct = 0; ct < 8; ++ct) {
            int c0 = ct * 16 + g * 4;
            float o[4];
            #pragma unroll
            for (int r = 0; r < 4; ++r) {
                float v = acc[ct][r] * zinv;
                o[r] = v > 0.f ? v : __expf(v) - 1.f;
            }
            unsigned long long pv =
                  (unsigned long long)packbf_rne(o[0], o[1])
                | ((unsigned long long)packbf_rne(o[2], o[3]) << 32);
            *(unsigned long long*)&x2[orow + c0] = pv;
        }
    } else {
        float o[8][4];
        float mx = -3.0e38f;
        #pragma unroll
        for (int ct = 0; ct < 8; ++ct) {
            #pragma unroll
            for (int r = 0; r < 4; ++r) {
                float v = acc[ct][r] * zinv;
                v = v > 0.f ? v : __expf(v) - 1.f;
                o[ct][r] = v;
                mx = fmaxf(mx, v);
            }
        }
        mx = fmaxf(mx, __shfl_xor(mx, 16, 64));
        mx = fmaxf(mx, __shfl_xor(mx, 32, 64));
        float s = 0.f;
        #pragma unroll
        for (int ct = 0; ct < 8; ++ct)
            #pragma unroll
            for (int r = 0; r < 4; ++r) s += __expf(o[ct][r] - mx);
        s += __shfl_xor(s, 16, 64);
        s += __shfl_xor(s, 32, 64);
        float lse = mx + __logf(s);
        #pragma unroll
        for (int ct = 0; ct < 8; ++ct) {
            float4 st = {o[ct][0] - lse, o[ct][1] - lse, o[ct][2] - lse, o[ct][3] - lse};
            *(float4*)&dout[((size_t)(b * 512 + i)) * 128 + ct * 16 + g * 4] = st;
        }
    }
}

extern "C" void kernel_launch(void* const* d_in, const int* in_sizes, int n_in,
                              void* d_out, int out_size, void* d_ws, size_t ws_size,
                              hipStream_t stream)
{
    const float* hs = (const float*)d_in[0];
    const float* os = (const float*)d_in[1];
    const float* Wh = (const float*)d_in[4];
    const float* ah = (const float*)d_in[5];
    const float* Wo = (const float*)d_in[6];
    const float* ao = (const float*)d_in[7];
    float* out = (float*)d_out;

    u16t* h1T = (u16t*)d_ws;             // 4,194,304 u16
    u16t* x2  = h1T + 4194304;           // 4,194,304 u16
    u16t* h2T = x2 + 4194304;            // 1,048,576 u16
    u16t* WoT = h2T + 1048576;           // 65,536 u16
    float* f1a = (float*)(WoT + 65536);  // 32,768 f32
    float* f2a = f1a + 32768;
    float* f1b = f2a + 32768;            // 8,192 f32
    float* f2b_ = f1b + 8192;

    proj1_kernel<<<256, 512, 0, stream>>>(hs, os, Wh, Wo, ah, h1T, WoT, f1a, f2a);
    attn_kernel<<<512, 256, 0, stream>>>(h1T, f1a, f2a, x2, nullptr, 0);
    proj2_kernel<<<128, 256, 0, stream>>>(x2, WoT, ao, h2T, f1b, f2b_);
    attn_kernel<<<64, 256, 0, stream>>>(h2T, f1b, f2b_, nullptr, out, 1);
}